// Round 9
// baseline (632.568 us; speedup 1.0000x reference)
//
#include <hip/hip_runtime.h>
#include <hip/hip_bf16.h>
#include <math.h>

// ---------------- problem constants ----------------
#define H      1280          // hidden == intermediate
#define NE     16            // total experts (2 shared + 14 routed)
#define NR     14            // routed experts
#define TK     4             // top-k routed per token
#define T      4096          // tokens (B*S = 2*2048)
#define NROWS  24576         // 2*T shared rows + 4*T routed rows
#define MAXT   112           // >= 32 shared + <=78 routed m-tiles of 256 rows
#define NT     (H / 32)      // 40 K-tiles of BK=32

typedef __bf16 bf16x8 __attribute__((ext_vector_type(8)));
typedef float  f32x4  __attribute__((ext_vector_type(4)));
typedef unsigned short us8 __attribute__((ext_vector_type(8)));

__device__ __forceinline__ unsigned short f2bf(float f) {
  unsigned int u = __float_as_uint(f);
  u += 0x7fffu + ((u >> 16) & 1u);
  return (unsigned short)(u >> 16);
}
__device__ __forceinline__ float bf2f(unsigned short u) {
  return __uint_as_float(((unsigned int)u) << 16);
}

// async 16B global->LDS (LDS dest must be wave-uniform base + lane*16)
__device__ __forceinline__ void gll16(const unsigned short* g, unsigned short* l) {
  __builtin_amdgcn_global_load_lds(
      (const __attribute__((address_space(1))) void*)g,
      (__attribute__((address_space(3))) void*)l, 16, 0, 0);
}

// ---------------- small setup kernels ----------------
__global__ void k_init(int* cnt, int* fill) {
  int i = threadIdx.x;
  if (i < 16) { cnt[i] = 0; fill[i] = 0; }
}

// Transpose+convert all 32 weight matrices: dst[n][k] = bf16(src[k][n]).
// LDS: [64][64] shorts, chunk-swizzled (r8: conflict-reduced, kept).
__global__ void k_transpose(const float* __restrict__ W1s, const float* __restrict__ W2s,
                            const float* __restrict__ W1r, const float* __restrict__ W2r,
                            unsigned short* __restrict__ w1b, unsigned short* __restrict__ w2b) {
  int mat = blockIdx.z;
  int fam = mat >> 4;       // 0 -> W1 family, 1 -> W2 family
  int e   = mat & 15;       // expert slot: 0,1 shared; 2..15 routed
  size_t msz = (size_t)H * H;
  const float* src;
  unsigned short* dst;
  if (fam == 0) {
    src = (e < 2) ? W1s + (size_t)e * msz : W1r + (size_t)(e - 2) * msz;
    dst = w1b + (size_t)e * msz;
  } else {
    src = (e < 2) ? W2s + (size_t)e * msz : W2r + (size_t)(e - 2) * msz;
    dst = w2b + (size_t)e * msz;
  }
  __shared__ unsigned short tile[64 * 64];    // swizzled [srcCol][srcRow]
  int tx = threadIdx.x & 15;                  // src col group (x4)
  int ty = threadIdx.x >> 4;                  // 0..15
  int bx = blockIdx.x * 64;                   // src col base
  int by = blockIdx.y * 64;                   // src row base
  int wsw = tx & 7;                           // write swizzle key ((cc>>2)&7 == tx&7)
#pragma unroll
  for (int p = 0; p < 4; p++) {
    int r = p * 16 + ty;
    float4 v = *reinterpret_cast<const float4*>(&src[(size_t)(by + r) * H + bx + tx * 4]);
    int slot = (((r >> 3) ^ wsw) << 3) + (r & 7);
    tile[(tx * 4 + 0) * 64 + slot] = f2bf(v.x);
    tile[(tx * 4 + 1) * 64 + slot] = f2bf(v.y);
    tile[(tx * 4 + 2) * 64 + slot] = f2bf(v.z);
    tile[(tx * 4 + 3) * 64 + slot] = f2bf(v.w);
  }
  __syncthreads();
  int tx8 = threadIdx.x & 7;                  // dst col group (x8) = r-chunk
  int rr  = threadIdx.x >> 3;                 // 0..31
#pragma unroll
  for (int p = 0; p < 2; p++) {
    int n = p * 32 + rr;                      // src col / dst row offset
    us8 o = *reinterpret_cast<const us8*>(&tile[n * 64 + ((tx8 ^ ((n >> 2) & 7)) << 3)]);
    *reinterpret_cast<us8*>(&dst[(size_t)(bx + n) * H + by + tx8 * 8]) = o;
  }
}

// ---------------- router: logits -> softmax -> top4; emits xb = bf16(x) + expert counts ----------------
__global__ void k_router(const float* __restrict__ x, const float* __restrict__ Wr,
                         const float* __restrict__ br,
                         int* __restrict__ topk_e, float* __restrict__ topk_g,
                         unsigned short* __restrict__ xb, int* __restrict__ cnt) {
  __shared__ int hist[NR];
  if (threadIdx.x < NR) hist[threadIdx.x] = 0;
  __syncthreads();
  int t  = blockIdx.x * 4 + (threadIdx.x >> 6);
  int ln = threadIdx.x & 63;
  float part[NR];
#pragma unroll
  for (int e = 0; e < NR; e++) part[e] = 0.f;
  const float* xr = x + (size_t)t * H;
  unsigned short* xw = xb + (size_t)t * H;
  for (int k = ln; k < H; k += 64) {
    float xv = xr[k];
    xw[k] = f2bf(xv);                          // fused bf16 cast of x
    const float* w = Wr + (size_t)k * NR;
#pragma unroll
    for (int e = 0; e < NR; e++) part[e] += xv * w[e];
  }
  float aff[NR];
#pragma unroll
  for (int e = 0; e < NR; e++) {
    float v = part[e];
#pragma unroll
    for (int off = 32; off; off >>= 1) v += __shfl_down(v, off);
    aff[e] = v + br[e];                        // valid on lane 0
  }
  if (ln == 0) {
    float mx = aff[0];
#pragma unroll
    for (int e = 1; e < NR; e++) mx = fmaxf(mx, aff[e]);
    float p[NR]; float s = 0.f;
#pragma unroll
    for (int e = 0; e < NR; e++) { p[e] = expf(aff[e] - mx); s += p[e]; }
    float inv = 1.f / s;
    unsigned used = 0;
    for (int j = 0; j < TK; j++) {
      int be = -1; float bv = -1.f;
#pragma unroll
      for (int e = 0; e < NR; e++)
        if (!((used >> e) & 1u) && p[e] > bv) { bv = p[e]; be = e; }  // ties -> lowest idx (jax top_k)
      used |= 1u << be;
      topk_e[t * TK + j] = be;
      topk_g[t * TK + j] = bv * inv;           // softmax gate, NOT renormalized
      atomicAdd(&hist[be], 1);                 // fused expert count (LDS)
    }
  }
  __syncthreads();
  if (threadIdx.x < NR) atomicAdd(&cnt[threadIdx.x], hist[threadIdx.x]);
}

// seg0 = shared0 [0,T), seg1 = shared1 [T,2T), seg 2+e = routed expert e. 256-row m-tiles.
__global__ void k_prefix(const int* __restrict__ cnt, int* __restrict__ segbase,
                         int* __restrict__ segcnt, int* __restrict__ tile_seg,
                         int* __restrict__ tile_m0) {
  if (threadIdx.x == 0) {
    int sc[NE];
    sc[0] = T; sc[1] = T;
    for (int e = 0; e < NR; e++) sc[2 + e] = cnt[e];
    int b = 0;
    for (int s = 0; s < NE; s++) { segbase[s] = b; segcnt[s] = sc[s]; b += sc[s]; }
    int nt = 0;
    for (int s = 0; s < NE; s++)
      for (int m = 0; m < sc[s]; m += 256) { tile_seg[nt] = s; tile_m0[nt] = m; nt++; }
    for (int i = nt; i < MAXT; i++) { tile_seg[i] = -1; tile_m0[i] = 0; }
  }
}

// scatter tokens to segment rows; LDS ranks + 224 global atomics
__global__ void k_fill(const int* __restrict__ topk_e,
                       const int* __restrict__ segbase, int* __restrict__ fill,
                       int* __restrict__ rowtok, int* __restrict__ tokrow) {
  __shared__ int lhist[NR];
  __shared__ int lbase[NR];
  int tid = threadIdx.x;
  if (tid < NR) lhist[tid] = 0;
  __syncthreads();
  int t = blockIdx.x * 256 + tid;
  rowtok[t]     = t;                            // shared expert 0
  rowtok[T + t] = t;                            // shared expert 1
  int e[TK], off[TK];
#pragma unroll
  for (int j = 0; j < TK; j++) {
    e[j]   = topk_e[t * TK + j];
    off[j] = atomicAdd(&lhist[e[j]], 1);        // intra-block rank (LDS atomic)
  }
  __syncthreads();
  if (tid < NR) lbase[tid] = atomicAdd(&fill[tid], lhist[tid]);  // block base
  __syncthreads();
#pragma unroll
  for (int j = 0; j < TK; j++) {
    int r = segbase[2 + e[j]] + lbase[e[j]] + off[j];
    rowtok[r] = t;
    tokrow[t * TK + j] = r;
  }
}

// ---------------- grouped GEMM: 256x256 tile, BK=32 dbuf -> 64 KB LDS -> 2 blocks/CU ----------------
// r3 schedule (best measured) with HALVED K-step so LDS = 2x(8+8) KB x2 = 64 KB:
// two blocks co-resident per CU. Block A's end-of-step vmcnt(0) drain is covered
// by block B's compute/issue (m114 cross-block overlap) — the concurrency the
// 128 KB config structurally lacked. 480 real blocks <= 512 slots -> ONE
// dispatch generation (r3 had two).
// Per K-tile t: STAGE(t+1) into buf[(t+1)&1] FIRST; compute buf[t&1]
// (12 ds_read_b128 + 32 MFMA); __syncthreads().
//
// LDS swizzle for 64 B rows (4 chunks of 16 B): chunk c of row r lives at slot
// c ^ ((r>>1)&3). Frag-read bank math: lanes split even/odd rows across bank
// halves, key spreads 8 lanes over 4 slots -> 2 lanes/bank = free (m136).
// Staging source chunk: (tid&3) ^ ((lrow>>1)&3) (involution, both sides agree).
// A frag: A[m=lane&15][k=quad*8+j]; B frag: B[k][n] (B stored N-major).
// C/D: col = lane&15, row = quad*4 + reg.

template<int MODE>   // 0 = gemm1 (rowtok gather + GELU), 1 = gemm2 (direct + bias)
__global__ __launch_bounds__(512, 2) void k_gemm(
    const unsigned short* __restrict__ Abase,   // xb (MODE 0) or hbuf (MODE 1)
    const unsigned short* __restrict__ Wb,      // w1b or w2b
    const float* __restrict__ bs, const float* __restrict__ brr,
    const int* __restrict__ rowtok,
    const int* __restrict__ segbase, const int* __restrict__ segcnt,
    const int* __restrict__ tile_seg, const int* __restrict__ tile_m0,
    unsigned short* __restrict__ obuf) {
  int seg = tile_seg[blockIdx.y];
  if (seg < 0) return;
  int m0  = tile_m0[blockIdx.y];
  int cnt = segcnt[seg];
  int n0  = blockIdx.x * 256;
  int sb  = segbase[seg];
  const unsigned short* Bw = Wb + (size_t)seg * H * H;
  const float* bias = (seg < 2) ? bs + (size_t)seg * H : brr + (size_t)(seg - 2) * H;

  __shared__ __align__(16) unsigned short Al[2][256 * 32];   // 2 x 16 KB
  __shared__ __align__(16) unsigned short Bl[2][256 * 32];   // 2 x 16 KB

  int tid = threadIdx.x;
  int wv = tid >> 6, ln = tid & 63;
  int rw = (wv & 1) * 128, cw = (wv >> 1) * 64;
  int quad = ln >> 4, l16 = ln & 15;
  int lrow = tid >> 2;                          // 0..127 staging row within pass
  int ldst = (tid & 3) * 8;                     // LDS slot (lane*16B contiguous)
  int lkc  = ((tid & 3) ^ ((lrow >> 1) & 3)) * 8;  // swizzled source chunk

  const unsigned short* asrc[2];
  const unsigned short* bsrc[2];
#pragma unroll
  for (int p = 0; p < 2; p++) {
    int row = p * 128 + lrow;                   // (row>>1)&3 == (lrow>>1)&3
    if (MODE == 0) {
      int gm  = m0 + row;
      int tok = (gm < cnt) ? rowtok[sb + gm] : 0;
      asrc[p] = Abase + (size_t)tok * H + lkc;
    } else {
      int ar = sb + m0 + row;
      if (ar >= NROWS) ar = 0;                  // clamp padding rows in-bounds
      asrc[p] = Abase + (size_t)ar * H + lkc;
    }
    bsrc[p] = Bw + (size_t)(n0 + row) * H + lkc;
  }

  int xsw = (quad ^ ((l16 >> 1) & 3)) * 8;      // swizzled frag read base (elems)

  f32x4 acc[8][4];
#pragma unroll
  for (int i = 0; i < 8; i++)
#pragma unroll
    for (int j = 0; j < 4; j++) acc[i][j] = (f32x4){0.f, 0.f, 0.f, 0.f};

  auto STAGE = [&](int tt) {
    int kb = tt << 5;                           // element offset along K (BK=32)
    unsigned short* Ad = &Al[tt & 1][0];
    unsigned short* Bd = &Bl[tt & 1][0];
#pragma unroll
    for (int p = 0; p < 2; p++) {
      int row = p * 128 + lrow;
      gll16(asrc[p] + kb, Ad + row * 32 + ldst);
      gll16(bsrc[p] + kb, Bd + row * 32 + ldst);
    }
  };

  STAGE(0);                                     // prologue: tile 0
  __syncthreads();                              // drains vmcnt(0): tile 0 landed

  for (int t = 0; t < NT; ++t) {
    if (t + 1 < NT) STAGE(t + 1);               // issue prefetch BEFORE compute
    const unsigned short* Ac = &Al[t & 1][0];
    const unsigned short* Bc = &Bl[t & 1][0];
    bf16x8 af[8], bfr[4];
#pragma unroll
    for (int i = 0; i < 8; i++)
      af[i] = *reinterpret_cast<const bf16x8*>(&Ac[(rw + i * 16 + l16) * 32 + xsw]);
#pragma unroll
    for (int j = 0; j < 4; j++)
      bfr[j] = *reinterpret_cast<const bf16x8*>(&Bc[(cw + j * 16 + l16) * 32 + xsw]);
#pragma unroll
    for (int i = 0; i < 8; i++)
#pragma unroll
      for (int j = 0; j < 4; j++)
        acc[i][j] = __builtin_amdgcn_mfma_f32_16x16x32_bf16(af[i], bfr[j], acc[i][j], 0, 0, 0);
    __syncthreads();                            // one drain per tile, AFTER compute
  }

  // ---- epilogue ----
#pragma unroll
  for (int i = 0; i < 8; i++) {
#pragma unroll
    for (int r = 0; r < 4; r++) {
      int m = m0 + rw + i * 16 + quad * 4 + r;
      if (m >= cnt) continue;
      size_t ro = (size_t)(sb + m) * H;
#pragma unroll
      for (int j = 0; j < 4; j++) {
        int n = n0 + cw + j * 16 + l16;
        float v = acc[i][j][r] + bias[n];
        if (MODE == 0) {
          float g = 0.5f * v * (1.f + erff(v * 0.70710678118654752f));   // exact-erf GELU
          obuf[ro + n] = f2bf(g);
        } else {
          obuf[ro + n] = f2bf(v);
        }
      }
    }
  }
}

// out[t] = x[t] + rbuf[t] + rbuf[T+t] + sum_j gate_j * rbuf[tokrow[t][j]]
__global__ void k_combine(const float* __restrict__ x, const unsigned short* __restrict__ rbuf,
                          const int* __restrict__ tokrow, const float* __restrict__ topk_g,
                          float* __restrict__ out) {
  int i = blockIdx.x * 256 + threadIdx.x;      // T*H/4 threads
  int t = i / (H / 4);
  int c = (i - t * (H / 4)) * 4;
  size_t xo = (size_t)t * H + c;
  float4 acc = *reinterpret_cast<const float4*>(&x[xo]);
  {
    ushort4 u0 = *reinterpret_cast<const ushort4*>(&rbuf[(size_t)t * H + c]);
    ushort4 u1 = *reinterpret_cast<const ushort4*>(&rbuf[(size_t)(T + t) * H + c]);
    acc.x += bf2f(u0.x) + bf2f(u1.x);
    acc.y += bf2f(u0.y) + bf2f(u1.y);
    acc.z += bf2f(u0.z) + bf2f(u1.z);
    acc.w += bf2f(u0.w) + bf2f(u1.w);
  }
#pragma unroll
  for (int j = 0; j < TK; j++) {
    int r   = tokrow[t * TK + j];
    float g = topk_g[t * TK + j];
    ushort4 u = *reinterpret_cast<const ushort4*>(&rbuf[(size_t)r * H + c]);
    acc.x += g * bf2f(u.x);
    acc.y += g * bf2f(u.y);
    acc.z += g * bf2f(u.z);
    acc.w += g * bf2f(u.w);
  }
  *reinterpret_cast<float4*>(&out[xo]) = acc;
}

// ---------------- host launch ----------------
extern "C" void kernel_launch(void* const* d_in, const int* in_sizes, int n_in,
                              void* d_out, int out_size, void* d_ws, size_t ws_size,
                              hipStream_t stream) {
  const float* x   = (const float*)d_in[0];
  const float* W1s = (const float*)d_in[1];
  const float* b1s = (const float*)d_in[2];
  const float* W2s = (const float*)d_in[3];
  const float* b2s = (const float*)d_in[4];
  const float* W1r = (const float*)d_in[5];
  const float* b1r = (const float*)d_in[6];
  const float* W2r = (const float*)d_in[7];
  const float* b2r = (const float*)d_in[8];
  const float* Wr  = (const float*)d_in[9];
  const float* br  = (const float*)d_in[10];
  float* out = (float*)d_out;

  char* ws = (char*)d_ws;
  const size_t SZ_XB = (size_t)T * H * 2;            // 10.49 MB
  const size_t SZ_WB = (size_t)NE * H * H * 2;       // 52.43 MB each
  const size_t SZ_H  = (size_t)NROWS * H * 2;        // 62.91 MB
  size_t off = 0;
  unsigned short* xb   = (unsigned short*)(ws + off); off += SZ_XB;
  unsigned short* w1b  = (unsigned short*)(ws + off); off += SZ_WB;
  unsigned short* w2b  = (unsigned short*)(ws + off); off += SZ_WB;
  unsigned short* hbuf = (unsigned short*)(ws + off); off += SZ_H;
  int*   rowtok  = (int*)(ws + off);   off += NROWS * 4;
  int*   tokrow  = (int*)(ws + off);   off += T * TK * 4;
  int*   topk_e  = (int*)(ws + off);   off += T * TK * 4;
  float* topk_g  = (float*)(ws + off); off += T * TK * 4;
  int*   cnt     = (int*)(ws + off);   off += 64;
  int*   fill    = (int*)(ws + off);   off += 64;
  int*   segbase = (int*)(ws + off);   off += 64;
  int*   segcnt  = (int*)(ws + off);   off += 64;
  int*   tile_seg = (int*)(ws + off);  off += MAXT * 4;
  int*   tile_m0  = (int*)(ws + off);  off += MAXT * 4;
  // rbuf aliases [xb][w1b] (exactly NROWS*H*2 bytes) — both dead once gemm2 runs.
  unsigned short* rbuf = (unsigned short*)ws;

  hipLaunchKernelGGL(k_init, dim3(1), dim3(64), 0, stream, cnt, fill);
  hipLaunchKernelGGL(k_transpose, dim3(20, 20, 32), dim3(256), 0, stream,
                     W1s, W2s, W1r, W2r, w1b, w2b);
  hipLaunchKernelGGL(k_router, dim3(T / 4), dim3(256), 0, stream,
                     x, Wr, br, topk_e, topk_g, xb, cnt);
  hipLaunchKernelGGL(k_prefix, dim3(1), dim3(1), 0, stream, cnt, segbase, segcnt, tile_seg, tile_m0);
  hipLaunchKernelGGL(k_fill, dim3(T / 256), dim3(256), 0, stream,
                     topk_e, segbase, fill, rowtok, tokrow);
  hipLaunchKernelGGL(HIP_KERNEL_NAME(k_gemm<0>), dim3(5, MAXT, 1), dim3(512), 0, stream,
                     xb, w1b, b1s, b1r, rowtok, segbase, segcnt, tile_seg, tile_m0, hbuf);
  hipLaunchKernelGGL(HIP_KERNEL_NAME(k_gemm<1>), dim3(5, MAXT, 1), dim3(512), 0, stream,
                     hbuf, w2b, b2s, b2r, rowtok, segbase, segcnt, tile_seg, tile_m0, rbuf);
  hipLaunchKernelGGL(k_combine, dim3((T * H / 4) / 256), dim3(256), 0, stream,
                     x, rbuf, tokrow, topk_g, out);
}